// Round 4
// baseline (443.261 us; speedup 1.0000x reference)
//
#include <hip/hip_runtime.h>
#include <hip/hip_bf16.h>
#include <stdint.h>

#define B_ 4
#define S_ 2048
#define E_ 1024
#define H_ 16
#define D_ 64
#define N_ (B_*S_)   // 8192

typedef __attribute__((ext_vector_type(4))) float f32x4;
typedef __attribute__((ext_vector_type(8))) short short8;

__device__ __forceinline__ ushort f2bf(float f) {
  uint32_t u = __float_as_uint(f);
  u += 0x7FFF + ((u >> 16) & 1);   // RNE; inputs are finite/normal
  return (ushort)(u >> 16);
}

__device__ __forceinline__ void gload_lds16(const void* g, void* l) {
  __builtin_amdgcn_global_load_lds((const __attribute__((address_space(1))) uint32_t*)g,
                                   (__attribute__((address_space(3))) uint32_t*)l,
                                   16, 0, 0);
}

// ---------------- fp32 -> bf16 cast, float4-vectorized ----------------
__global__ void cast_bf16_kernel(const float* __restrict__ in,
                                 ushort* __restrict__ out, int n4) {
  int i = blockIdx.x * blockDim.x + threadIdx.x;
  if (i >= n4) return;
  float4 f = ((const float4*)in)[i];
  ushort4 o;
  o.x = f2bf(f.x); o.y = f2bf(f.y); o.z = f2bf(f.z); o.w = f2bf(f.w);
  ((ushort4*)out)[i] = o;
}

// ---------------- bf16 NT GEMM: C = A[Nr,1024] * W[1024,1024]^T + bias --------
// m97 structure: 128x128 tile, BK=64, 4 waves (2x2), 4x4 16x16x32 frags/wave,
// global_load_lds width-16 staging into linear LDS, 2-barrier K-loop.
// EPI: 0 = bf16 to [B,H,S,D] (Q/K)   1 = bf16 to [B,H,D,S] (V transposed)
//      2 = fp32 to [Nr,1024] (final output)
template<int EPI>
__global__ __launch_bounds__(256)
void gemm_bt(const ushort* __restrict__ A, const ushort* __restrict__ Bw,
             const float* __restrict__ bias, void* __restrict__ Cout) {
  __shared__ ushort lA[128*64];
  __shared__ ushort lB[128*64];
  const int t = threadIdx.x;
  const int lane = t & 63;
  const int wave = t >> 6;
  const int wr = wave >> 1, wc = wave & 1;
  const int g = lane >> 4, li = lane & 15;
  const int row0 = blockIdx.x * 128, col0 = blockIdx.y * 128;

  const ushort* Ab = A + (size_t)row0 * E_;
  const ushort* Bb = Bw + (size_t)col0 * E_;

  f32x4 acc[4][4] = {};

  for (int kt = 0; kt < E_; kt += 64) {
    __syncthreads();                       // LDS reuse fence
    for (int i = 0; i < 4; ++i) {
      int id = i*256 + t;                  // 16B chunk id, 0..1023
      int r  = id >> 3;                    // tile row 0..127
      int c  = (id & 7) * 8;               // bf16 col offset within BK=64
      // dst is wave-uniform base; HW scatters lane*16B (linear layout required)
      gload_lds16(Ab + (size_t)r*E_ + kt + c, (char*)lA + (i*256 + wave*64)*16);
      gload_lds16(Bb + (size_t)r*E_ + kt + c, (char*)lB + (i*256 + wave*64)*16);
    }
    __syncthreads();                       // drains vmcnt before barrier
    for (int ks = 0; ks < 2; ++ks) {
      const int ko = ks*32 + g*8;
      short8 af[4], bf[4];
      for (int mi = 0; mi < 4; ++mi)
        af[mi] = *(const short8*)&lA[(wr*64 + mi*16 + li)*64 + ko];
      for (int ni = 0; ni < 4; ++ni)
        bf[ni] = *(const short8*)&lB[(wc*64 + ni*16 + li)*64 + ko];
      for (int mi = 0; mi < 4; ++mi)
        for (int ni = 0; ni < 4; ++ni)
          acc[mi][ni] = __builtin_amdgcn_mfma_f32_16x16x32_bf16(
                            af[mi], bf[ni], acc[mi][ni], 0, 0, 0);
    }
  }

  // epilogue: C elem (row = .. + g*4 + j, col = .. + li), fused bias + layout
  for (int mi = 0; mi < 4; ++mi)
    for (int ni = 0; ni < 4; ++ni) {
      const int ccol = col0 + wc*64 + ni*16 + li;
      const float bv = bias[ccol];
      const int r0 = row0 + wr*64 + mi*16 + g*4;     // j=0..3 are consecutive rows
      if (EPI == 1) {
        // V^T write: 4 consecutive s -> one aligned ushort4 store per (mi,ni)
        int b = r0 >> 11, s = r0 & (S_-1), h = ccol >> 6, d = ccol & 63;
        ushort4 pk;
        pk.x = f2bf(acc[mi][ni][0] + bv);
        pk.y = f2bf(acc[mi][ni][1] + bv);
        pk.z = f2bf(acc[mi][ni][2] + bv);
        pk.w = f2bf(acc[mi][ni][3] + bv);
        *(ushort4*)&((ushort*)Cout)[((((size_t)b*H_ + h)*D_ + d) << 11) + s] = pk;
      } else {
        for (int j = 0; j < 4; ++j) {
          const int r = r0 + j;
          const float v = acc[mi][ni][j] + bv;
          if (EPI == 0) {
            int b = r >> 11, s = r & (S_-1), h = ccol >> 6, d = ccol & 63;
            ((ushort*)Cout)[((((size_t)b*H_ + h)*S_ + s) << 6) + d] = f2bf(v);
          } else {
            ((float*)Cout)[(size_t)r*E_ + ccol] = v;   // lanes li coalesce to 64B
          }
        }
      }
    }
}

// ---------------- causal flash attention ----------------
// block = 64 q-rows of one (b,h); 4 waves x 16 rows. KV tiles of 64.
// K rows + V^T rows staged in LDS padded to 72 shorts (kills stride-128B
// 16-way bank conflict). Softmax wave-parallel via 16-lane shfl_xor groups.
__global__ __launch_bounds__(256)
void attn_kernel(const ushort* __restrict__ q, const ushort* __restrict__ k,
                 const ushort* __restrict__ vt, ushort* __restrict__ ao) {
  const int qb = blockIdx.x;
  const int bh = blockIdx.y;
  const int b = bh >> 4, h = bh & 15;
  const int t = threadIdx.x, lane = t & 63, wave = t >> 6;
  const int g = lane >> 4, li = lane & 15;
  const int q0 = qb * 64;
  const int qrow0 = q0 + wave * 16;

  __shared__ ushort lK[64*72];
  __shared__ ushort lV[64*72];     // lV[d][s] (V pre-transposed in global)
  __shared__ ushort lP[4][16*72];  // per-wave P tile

  const ushort* qp = q  + (size_t)bh * S_ * D_;
  const ushort* kp = k  + (size_t)bh * S_ * D_;
  const ushort* vp = vt + (size_t)bh * D_ * S_;

  short8 qf[2];
  for (int ks = 0; ks < 2; ++ks)
    qf[ks] = *(const short8*)&qp[(size_t)(qrow0 + li)*D_ + ks*32 + g*8];

  f32x4 o[4] = {};
  float m_i[4], l_i[4];
  for (int j = 0; j < 4; ++j) { m_i[j] = -1e30f; l_i[j] = 0.f; }

  const int nkt = qb + 1;                  // causal: only tiles with k0 <= q0+63
  for (int kt = 0; kt < nkt; ++kt) {
    const int k0 = kt * 64;
    __syncthreads();
    {
      const int r = t >> 2;
      const int c = (t & 3) * 16;          // 32B per thread, 2x short8
      *(short8*)&lK[r*72 + c]     = *(const short8*)&kp[(size_t)(k0 + r)*D_ + c];
      *(short8*)&lK[r*72 + c + 8] = *(const short8*)&kp[(size_t)(k0 + r)*D_ + c + 8];
      *(short8*)&lV[r*72 + c]     = *(const short8*)&vp[(size_t)r*S_ + k0 + c];
      *(short8*)&lV[r*72 + c + 8] = *(const short8*)&vp[(size_t)r*S_ + k0 + c + 8];
    }
    __syncthreads();

    if (k0 <= qrow0 + 15) {                // wave-uniform skip of masked tiles
      // S = Q K^T  (A=Q frags, B=K rows)
      f32x4 s4[4] = {};
      for (int ks = 0; ks < 2; ++ks) {
        const int ko = ks*32 + g*8;
        for (int ct = 0; ct < 4; ++ct) {
          short8 kf = *(const short8*)&lK[(ct*16 + li)*72 + ko];
          s4[ct] = __builtin_amdgcn_mfma_f32_16x16x32_bf16(qf[ks], kf, s4[ct], 0,0,0);
        }
      }
      // mask + online softmax; C elem: row=g*4+j (q), col=ct*16+li (k)
      float sv[4][4];
      float mnew[4] = {-1e30f, -1e30f, -1e30f, -1e30f};
      for (int ct = 0; ct < 4; ++ct) {
        const int col = k0 + ct*16 + li;
        for (int j = 0; j < 4; ++j) {
          const int row = qrow0 + g*4 + j;
          float x = s4[ct][j] * 0.125f;
          x = (col <= row) ? x : -1e30f;
          sv[ct][j] = x;
          mnew[j] = fmaxf(mnew[j], x);
        }
      }
      for (int off = 1; off < 16; off <<= 1)
        for (int j = 0; j < 4; ++j)
          mnew[j] = fmaxf(mnew[j], __shfl_xor(mnew[j], off, 64));
      float alpha[4];
      for (int j = 0; j < 4; ++j) {
        const float mn = fmaxf(m_i[j], mnew[j]);
        alpha[j] = __expf(m_i[j] - mn);
        m_i[j] = mn;
      }
      float rs[4] = {0.f, 0.f, 0.f, 0.f};
      for (int ct = 0; ct < 4; ++ct)
        for (int j = 0; j < 4; ++j) {
          const float p = __expf(sv[ct][j] - m_i[j]);
          sv[ct][j] = p;
          rs[j] += p;
        }
      for (int off = 1; off < 16; off <<= 1)
        for (int j = 0; j < 4; ++j)
          rs[j] += __shfl_xor(rs[j], off, 64);
      for (int j = 0; j < 4; ++j) l_i[j] = l_i[j]*alpha[j] + rs[j];
      for (int dt = 0; dt < 4; ++dt)
        for (int j = 0; j < 4; ++j) o[dt][j] *= alpha[j];

      // P -> LDS (bf16), then O += P * V  (A=P frags, B=V^T rows)
      for (int ct = 0; ct < 4; ++ct)
        for (int j = 0; j < 4; ++j)
          lP[wave][(g*4 + j)*72 + ct*16 + li] = f2bf(sv[ct][j]);
      for (int ks2 = 0; ks2 < 2; ++ks2) {
        short8 pf = *(const short8*)&lP[wave][li*72 + ks2*32 + g*8];
        for (int dt = 0; dt < 4; ++dt) {
          short8 vf = *(const short8*)&lV[(dt*16 + li)*72 + ks2*32 + g*8];
          o[dt] = __builtin_amdgcn_mfma_f32_16x16x32_bf16(pf, vf, o[dt], 0,0,0);
        }
      }
    }
  }

  // finalize: O /= l, write bf16 [B,S,E] with E = h*64+d
  for (int dt = 0; dt < 4; ++dt) {
    const int d = dt*16 + li;
    for (int j = 0; j < 4; ++j) {
      const int srow = qrow0 + g*4 + j;
      const float val = o[dt][j] / l_i[j];
      ao[((size_t)b*S_ + srow)*E_ + h*D_ + d] = f2bf(val);
    }
  }
}

// ---------------- launch ----------------
extern "C" void kernel_launch(void* const* d_in, const int* in_sizes, int n_in,
                              void* d_out, int out_size, void* d_ws, size_t ws_size,
                              hipStream_t stream) {
  (void)in_sizes; (void)n_in; (void)out_size; (void)ws_size;
  const float* x  = (const float*)d_in[0];
  const float* Wq = (const float*)d_in[1];
  const float* bq = (const float*)d_in[2];
  const float* Wk = (const float*)d_in[3];
  const float* bk = (const float*)d_in[4];
  const float* Wv = (const float*)d_in[5];
  const float* bv = (const float*)d_in[6];
  const float* Wo = (const float*)d_in[7];
  const float* bo = (const float*)d_in[8];
  float* out = (float*)d_out;

  char* ws = (char*)d_ws;
  ushort* xb  = (ushort*)(ws);                    // x bf16          16 MB
  ushort* wqb = (ushort*)(ws + 16777216);         // Wq bf16          2 MB
  ushort* wkb = (ushort*)(ws + 18874368);
  ushort* wvb = (ushort*)(ws + 20971520);
  ushort* wob = (ushort*)(ws + 23068672);
  ushort* qb_ = (ushort*)(ws + 25165824);         // Q [B,H,S,D]     16 MB
  ushort* kb_ = (ushort*)(ws + 41943040);         // K [B,H,S,D]     16 MB
  ushort* vtb = (ushort*)(ws + 58720256);         // V [B,H,D,S]     16 MB
  ushort* aob = xb;                               // attn out aliases xb (x dead)
  // total ws use: 75,497,472 B

  cast_bf16_kernel<<<8192, 256, 0, stream>>>(x,  xb,  N_*E_/4);
  cast_bf16_kernel<<<1024, 256, 0, stream>>>(Wq, wqb, E_*E_/4);
  cast_bf16_kernel<<<1024, 256, 0, stream>>>(Wk, wkb, E_*E_/4);
  cast_bf16_kernel<<<1024, 256, 0, stream>>>(Wv, wvb, E_*E_/4);
  cast_bf16_kernel<<<1024, 256, 0, stream>>>(Wo, wob, E_*E_/4);

  dim3 gg(N_/128, E_/128);   // 64 x 8
  gemm_bt<0><<<gg, 256, 0, stream>>>(xb, wqb, bq, qb_);
  gemm_bt<0><<<gg, 256, 0, stream>>>(xb, wkb, bk, kb_);
  gemm_bt<1><<<gg, 256, 0, stream>>>(xb, wvb, bv, vtb);

  attn_kernel<<<dim3(S_/64, B_*H_), 256, 0, stream>>>(qb_, kb_, vtb, aob);

  gemm_bt<2><<<gg, 256, 0, stream>>>(aob, wob, bo, out);
}

// Round 9
// 394.068 us; speedup vs baseline: 1.1248x; 1.1248x over previous
//
#include <hip/hip_runtime.h>
#include <hip/hip_bf16.h>
#include <stdint.h>

#define B_ 4
#define S_ 2048
#define E_ 1024
#define H_ 16
#define D_ 64
#define N_ (B_*S_)   // 8192

typedef __attribute__((ext_vector_type(4))) float f32x4;
typedef __attribute__((ext_vector_type(8))) short short8;

__device__ __forceinline__ ushort f2bf(float f) {
  uint32_t u = __float_as_uint(f);
  u += 0x7FFF + ((u >> 16) & 1);   // RNE; inputs are finite/normal
  return (ushort)(u >> 16);
}

__device__ __forceinline__ void gload_lds16(const void* g, void* l) {
  __builtin_amdgcn_global_load_lds((const __attribute__((address_space(1))) uint32_t*)g,
                                   (__attribute__((address_space(3))) uint32_t*)l,
                                   16, 0, 0);
}

// ---------------- fp32 -> bf16 cast, float4-vectorized ----------------
__global__ void cast_bf16_kernel(const float* __restrict__ in,
                                 ushort* __restrict__ out, int n4) {
  int i = blockIdx.x * blockDim.x + threadIdx.x;
  if (i >= n4) return;
  float4 f = ((const float4*)in)[i];
  ushort4 o;
  o.x = f2bf(f.x); o.y = f2bf(f.y); o.z = f2bf(f.z); o.w = f2bf(f.w);
  ((ushort4*)out)[i] = o;
}

// ---------------- bf16 NT GEMM: C = A[Nr,1024] * W[1024,1024]^T + bias --------
// m97 structure (unchanged — verified passing in round 4).
template<int EPI>
__global__ __launch_bounds__(256)
void gemm_bt(const ushort* __restrict__ A, const ushort* __restrict__ Bw,
             const float* __restrict__ bias, void* __restrict__ Cout) {
  __shared__ ushort lA[128*64];
  __shared__ ushort lB[128*64];
  const int t = threadIdx.x;
  const int lane = t & 63;
  const int wave = t >> 6;
  const int wr = wave >> 1, wc = wave & 1;
  const int g = lane >> 4, li = lane & 15;
  const int row0 = blockIdx.x * 128, col0 = blockIdx.y * 128;

  const ushort* Ab = A + (size_t)row0 * E_;
  const ushort* Bb = Bw + (size_t)col0 * E_;

  f32x4 acc[4][4] = {};

  for (int kt = 0; kt < E_; kt += 64) {
    __syncthreads();
    for (int i = 0; i < 4; ++i) {
      int id = i*256 + t;
      int r  = id >> 3;
      int c  = (id & 7) * 8;
      gload_lds16(Ab + (size_t)r*E_ + kt + c, (char*)lA + (i*256 + wave*64)*16);
      gload_lds16(Bb + (size_t)r*E_ + kt + c, (char*)lB + (i*256 + wave*64)*16);
    }
    __syncthreads();
    for (int ks = 0; ks < 2; ++ks) {
      const int ko = ks*32 + g*8;
      short8 af[4], bf[4];
      for (int mi = 0; mi < 4; ++mi)
        af[mi] = *(const short8*)&lA[(wr*64 + mi*16 + li)*64 + ko];
      for (int ni = 0; ni < 4; ++ni)
        bf[ni] = *(const short8*)&lB[(wc*64 + ni*16 + li)*64 + ko];
      for (int mi = 0; mi < 4; ++mi)
        for (int ni = 0; ni < 4; ++ni)
          acc[mi][ni] = __builtin_amdgcn_mfma_f32_16x16x32_bf16(
                            af[mi], bf[ni], acc[mi][ni], 0, 0, 0);
    }
  }

  for (int mi = 0; mi < 4; ++mi)
    for (int ni = 0; ni < 4; ++ni) {
      const int ccol = col0 + wc*64 + ni*16 + li;
      const float bv = bias[ccol];
      const int r0 = row0 + wr*64 + mi*16 + g*4;
      if (EPI == 1) {
        int b = r0 >> 11, s = r0 & (S_-1), h = ccol >> 6, d = ccol & 63;
        ushort4 pk;
        pk.x = f2bf(acc[mi][ni][0] + bv);
        pk.y = f2bf(acc[mi][ni][1] + bv);
        pk.z = f2bf(acc[mi][ni][2] + bv);
        pk.w = f2bf(acc[mi][ni][3] + bv);
        *(ushort4*)&((ushort*)Cout)[((((size_t)b*H_ + h)*D_ + d) << 11) + s] = pk;
      } else {
        for (int j = 0; j < 4; ++j) {
          const int r = r0 + j;
          const float v = acc[mi][ni][j] + bv;
          if (EPI == 0) {
            int b = r >> 11, s = r & (S_-1), h = ccol >> 6, d = ccol & 63;
            ((ushort*)Cout)[((((size_t)b*H_ + h)*S_ + s) << 6) + d] = f2bf(v);
          } else {
            ((float*)Cout)[(size_t)r*E_ + ccol] = v;
          }
        }
      }
    }
}

// ---------------- causal flash attention (restructured) ----------------
// Block = 128 q-rows of one (b,h); 4 waves x 32 rows (mq=2 sub-tiles of 16).
// Swapped QK^T: st = mfma(K,Q) -> lane li owns q-row (qrow0+mq*16+li); softmax
// reduce = 15 local fmax + 2 shfl_xor (vs 4-step x 8 chains before).
// PV computed as O^T = mfma(V^T, P^T) -> O stays in li=q domain: alpha & l are
// lane-local scalars (no cross-lane gathers).
// T14 async staging: global->reg issue before compute, reg->LDS after barrier.
__global__ __launch_bounds__(256)
void attn_kernel(const ushort* __restrict__ q, const ushort* __restrict__ k,
                 const ushort* __restrict__ vt, ushort* __restrict__ ao) {
  const int qb = blockIdx.x;               // 16 blocks of 128 q-rows
  const int bh = blockIdx.y;
  const int b = bh >> 4, h = bh & 15;
  const int t = threadIdx.x, lane = t & 63, wave = t >> 6;
  const int g = lane >> 4, li = lane & 15;
  const int qrow0 = qb*128 + wave*32;      // this wave's first q-row

  __shared__ ushort lK[64*72];             // K rows [k_local][d], pad 72
  __shared__ ushort lV[64*72];             // V^T rows [d][k_local], pad 72
  __shared__ ushort lP[4][16*72];          // per-wave P [q_local=li][k_local]

  const ushort* qp = q  + (size_t)bh * S_ * D_;
  const ushort* kp = k  + (size_t)bh * S_ * D_;
  const ushort* vp = vt + (size_t)bh * D_ * S_;

  // Q fragments (B-operand): lane li holds Q[qrow0+mq*16+li][ks*32+g*8 ..+7]
  short8 qf[2][2];
  for (int mq = 0; mq < 2; ++mq)
    for (int ks = 0; ks < 2; ++ks)
      qf[mq][ks] = *(const short8*)&qp[(size_t)(qrow0 + mq*16 + li)*D_ + ks*32 + g*8];

  f32x4 o[2][4] = {};                      // o[mq][dt]: O[q=li-row][d=dt*16+g*4+j]
  float m_i[2] = {-3e38f, -3e38f};
  float l_i[2] = {0.f, 0.f};

  const int sr = t >> 2;                   // staging row 0..63
  const int sc = (t & 3) * 16;             // staging col 0/16/32/48

  short8 rK0, rK1, rV0, rV1;               // staging registers (T14 split)
  // prologue: load tile 0
  rK0 = *(const short8*)&kp[(size_t)sr*D_ + sc];
  rK1 = *(const short8*)&kp[(size_t)sr*D_ + sc + 8];
  rV0 = *(const short8*)&vp[(size_t)sr*S_ + sc];
  rV1 = *(const short8*)&vp[(size_t)sr*S_ + sc + 8];

  const int nkt = 2*qb + 2;                // causal: k0 <= qb*128+127
  for (int kt = 0; kt < nkt; ++kt) {
    const int k0 = kt * 64;
    __syncthreads();                       // consumers of previous tile done
    *(short8*)&lK[sr*72 + sc]     = rK0;
    *(short8*)&lK[sr*72 + sc + 8] = rK1;
    *(short8*)&lV[sr*72 + sc]     = rV0;
    *(short8*)&lV[sr*72 + sc + 8] = rV1;
    __syncthreads();                       // tile visible
    if (kt + 1 < nkt) {                    // prefetch next tile (hides latency)
      const int kn = k0 + 64;
      rK0 = *(const short8*)&kp[(size_t)(kn + sr)*D_ + sc];
      rK1 = *(const short8*)&kp[(size_t)(kn + sr)*D_ + sc + 8];
      rV0 = *(const short8*)&vp[(size_t)sr*S_ + kn + sc];
      rV1 = *(const short8*)&vp[(size_t)sr*S_ + kn + sc + 8];
    }

    if (k0 > qrow0 + 31) continue;         // wave-uniform: fully masked

    // S^T tile: st[mq][ct] = K * Q^T ; lane holds S[k=k0+ct*16+g*4+j][q=li-row]
    f32x4 st[2][4] = {};
    for (int ks = 0; ks < 2; ++ks)
      for (int ct = 0; ct < 4; ++ct) {
        short8 kf = *(const short8*)&lK[(ct*16 + li)*72 + ks*32 + g*8];
        st[0][ct] = __builtin_amdgcn_mfma_f32_16x16x32_bf16(kf, qf[0][ks], st[0][ct], 0,0,0);
        st[1][ct] = __builtin_amdgcn_mfma_f32_16x16x32_bf16(kf, qf[1][ks], st[1][ct], 0,0,0);
      }

    for (int mq = 0; mq < 2; ++mq) {
      if (k0 > qrow0 + mq*16 + 15) continue;   // wave-uniform sub-tile skip
      const int qrow = qrow0 + mq*16 + li;     // this lane's q-row
      // mask + scale + local max over this lane's 16 k-values
      float mx = -3e38f;
      for (int ct = 0; ct < 4; ++ct)
        for (int j = 0; j < 4; ++j) {
          const int kk = k0 + ct*16 + g*4 + j;
          float x = st[mq][ct][j] * 0.125f;
          x = (kk <= qrow) ? x : -3e38f;
          st[mq][ct][j] = x;
          mx = fmaxf(mx, x);
        }
      mx = fmaxf(mx, __shfl_xor(mx, 16, 64));
      mx = fmaxf(mx, __shfl_xor(mx, 32, 64));
      const float mn = fmaxf(m_i[mq], mx);
      const float alpha = __expf(m_i[mq] - mn);
      m_i[mq] = mn;
      // P = exp(S - m), row-sum, pack to lP (b32 pairs)
      float rs = 0.f;
      for (int ct = 0; ct < 4; ++ct) {
        float p0 = __expf(st[mq][ct][0] - mn);
        float p1 = __expf(st[mq][ct][1] - mn);
        float p2 = __expf(st[mq][ct][2] - mn);
        float p3 = __expf(st[mq][ct][3] - mn);
        rs += (p0 + p1) + (p2 + p3);
        uint32_t w0 = (uint32_t)f2bf(p0) | ((uint32_t)f2bf(p1) << 16);
        uint32_t w1 = (uint32_t)f2bf(p2) | ((uint32_t)f2bf(p3) << 16);
        *(uint32_t*)&lP[wave][li*72 + ct*16 + g*4]     = w0;
        *(uint32_t*)&lP[wave][li*72 + ct*16 + g*4 + 2] = w1;
      }
      rs += __shfl_xor(rs, 16, 64);
      rs += __shfl_xor(rs, 32, 64);
      l_i[mq] = l_i[mq]*alpha + rs;
      // rescale O (lane-local alpha)
      for (int dt = 0; dt < 4; ++dt)
        for (int j = 0; j < 4; ++j) o[mq][dt][j] *= alpha;
      // O^T += V^T * P^T  (A = V^T rows, B = P^T cols = lP rows; same-wave
      // lP write->read ordered by lgkmcnt, no barrier needed)
      for (int ks2 = 0; ks2 < 2; ++ks2) {
        short8 pf = *(const short8*)&lP[wave][li*72 + ks2*32 + g*8];
        for (int dt = 0; dt < 4; ++dt) {
          short8 vf = *(const short8*)&lV[(dt*16 + li)*72 + ks2*32 + g*8];
          o[mq][dt] = __builtin_amdgcn_mfma_f32_16x16x32_bf16(vf, pf, o[mq][dt], 0,0,0);
        }
      }
    }
  }

  // finalize: O /= l (lane-local), write bf16 [B,S,E]; 4 consecutive d -> ushort4
  for (int mq = 0; mq < 2; ++mq) {
    const float inv_l = 1.0f / l_i[mq];
    const int row = qrow0 + mq*16 + li;
    for (int dt = 0; dt < 4; ++dt) {
      ushort4 pk;
      pk.x = f2bf(o[mq][dt][0] * inv_l);
      pk.y = f2bf(o[mq][dt][1] * inv_l);
      pk.z = f2bf(o[mq][dt][2] * inv_l);
      pk.w = f2bf(o[mq][dt][3] * inv_l);
      *(ushort4*)&ao[((size_t)b*S_ + row)*E_ + h*D_ + dt*16 + g*4] = pk;
    }
  }
}

// ---------------- launch ----------------
extern "C" void kernel_launch(void* const* d_in, const int* in_sizes, int n_in,
                              void* d_out, int out_size, void* d_ws, size_t ws_size,
                              hipStream_t stream) {
  (void)in_sizes; (void)n_in; (void)out_size; (void)ws_size;
  const float* x  = (const float*)d_in[0];
  const float* Wq = (const float*)d_in[1];
  const float* bq = (const float*)d_in[2];
  const float* Wk = (const float*)d_in[3];
  const float* bk = (const float*)d_in[4];
  const float* Wv = (const float*)d_in[5];
  const float* bv = (const float*)d_in[6];
  const float* Wo = (const float*)d_in[7];
  const float* bo = (const float*)d_in[8];
  float* out = (float*)d_out;

  char* ws = (char*)d_ws;
  ushort* xb  = (ushort*)(ws);                    // x bf16          16 MB
  ushort* wqb = (ushort*)(ws + 16777216);         // Wq bf16          2 MB
  ushort* wkb = (ushort*)(ws + 18874368);
  ushort* wvb = (ushort*)(ws + 20971520);
  ushort* wob = (ushort*)(ws + 23068672);
  ushort* qb_ = (ushort*)(ws + 25165824);         // Q [B,H,S,D]     16 MB
  ushort* kb_ = (ushort*)(ws + 41943040);         // K [B,H,S,D]     16 MB
  ushort* vtb = (ushort*)(ws + 58720256);         // V [B,H,D,S]     16 MB
  ushort* aob = xb;                               // attn out aliases xb (x dead)

  cast_bf16_kernel<<<8192, 256, 0, stream>>>(x,  xb,  N_*E_/4);
  cast_bf16_kernel<<<1024, 256, 0, stream>>>(Wq, wqb, E_*E_/4);
  cast_bf16_kernel<<<1024, 256, 0, stream>>>(Wk, wkb, E_*E_/4);
  cast_bf16_kernel<<<1024, 256, 0, stream>>>(Wv, wvb, E_*E_/4);
  cast_bf16_kernel<<<1024, 256, 0, stream>>>(Wo, wob, E_*E_/4);

  dim3 gg(N_/128, E_/128);   // 64 x 8
  gemm_bt<0><<<gg, 256, 0, stream>>>(xb, wqb, bq, qb_);
  gemm_bt<0><<<gg, 256, 0, stream>>>(xb, wkb, bk, kb_);
  gemm_bt<1><<<gg, 256, 0, stream>>>(xb, wvb, bv, vtb);

  attn_kernel<<<dim3(S_/128, B_*H_), 256, 0, stream>>>(qb_, kb_, vtb, aob);

  gemm_bt<2><<<gg, 256, 0, stream>>>(aob, wob, bo, out);
}

// Round 11
// 334.753 us; speedup vs baseline: 1.3241x; 1.1772x over previous
//
#include <hip/hip_runtime.h>
#include <hip/hip_bf16.h>
#include <stdint.h>

#define B_ 4
#define S_ 2048
#define E_ 1024
#define H_ 16
#define D_ 64
#define N_ (B_*S_)   // 8192

typedef __attribute__((ext_vector_type(4))) float f32x4;
typedef __attribute__((ext_vector_type(8))) short short8;

__device__ __forceinline__ ushort f2bf(float f) {
  uint32_t u = __float_as_uint(f);
  u += 0x7FFF + ((u >> 16) & 1);   // RNE; inputs are finite/normal
  return (ushort)(u >> 16);
}

__device__ __forceinline__ void gload_lds16(const void* g, void* l) {
  __builtin_amdgcn_global_load_lds((const __attribute__((address_space(1))) uint32_t*)g,
                                   (__attribute__((address_space(3))) uint32_t*)l,
                                   16, 0, 0);
}

// ---------------- fp32 -> bf16 cast, float4-vectorized ----------------
__global__ void cast_bf16_kernel(const float* __restrict__ in,
                                 ushort* __restrict__ out, int n4) {
  int i = blockIdx.x * blockDim.x + threadIdx.x;
  if (i >= n4) return;
  float4 f = ((const float4*)in)[i];
  ushort4 o;
  o.x = f2bf(f.x); o.y = f2bf(f.y); o.z = f2bf(f.z); o.w = f2bf(f.w);
  ((ushort4*)out)[i] = o;
}

// ---------------- bf16 NT GEMM: C = (A*W^T + bias)*oscale ----------------
// m97 structure (verified passing r4/r9). oscale: 1.0 except Q-projection,
// which folds the attention softmax scale 0.125*log2(e) into Q itself.
template<int EPI>
__global__ __launch_bounds__(256)
void gemm_bt(const ushort* __restrict__ A, const ushort* __restrict__ Bw,
             const float* __restrict__ bias, void* __restrict__ Cout,
             float oscale) {
  __shared__ ushort lA[128*64];
  __shared__ ushort lB[128*64];
  const int t = threadIdx.x;
  const int lane = t & 63;
  const int wave = t >> 6;
  const int wr = wave >> 1, wc = wave & 1;
  const int g = lane >> 4, li = lane & 15;
  const int row0 = blockIdx.x * 128, col0 = blockIdx.y * 128;

  const ushort* Ab = A + (size_t)row0 * E_;
  const ushort* Bb = Bw + (size_t)col0 * E_;

  f32x4 acc[4][4] = {};

  for (int kt = 0; kt < E_; kt += 64) {
    __syncthreads();
    for (int i = 0; i < 4; ++i) {
      int id = i*256 + t;
      int r  = id >> 3;
      int c  = (id & 7) * 8;
      gload_lds16(Ab + (size_t)r*E_ + kt + c, (char*)lA + (i*256 + wave*64)*16);
      gload_lds16(Bb + (size_t)r*E_ + kt + c, (char*)lB + (i*256 + wave*64)*16);
    }
    __syncthreads();
    for (int ks = 0; ks < 2; ++ks) {
      const int ko = ks*32 + g*8;
      short8 af[4], bf[4];
      for (int mi = 0; mi < 4; ++mi)
        af[mi] = *(const short8*)&lA[(wr*64 + mi*16 + li)*64 + ko];
      for (int ni = 0; ni < 4; ++ni)
        bf[ni] = *(const short8*)&lB[(wc*64 + ni*16 + li)*64 + ko];
      for (int mi = 0; mi < 4; ++mi)
        for (int ni = 0; ni < 4; ++ni)
          acc[mi][ni] = __builtin_amdgcn_mfma_f32_16x16x32_bf16(
                            af[mi], bf[ni], acc[mi][ni], 0, 0, 0);
    }
  }

  for (int mi = 0; mi < 4; ++mi)
    for (int ni = 0; ni < 4; ++ni) {
      const int ccol = col0 + wc*64 + ni*16 + li;
      const float bv = bias[ccol];
      const int r0 = row0 + wr*64 + mi*16 + g*4;
      if (EPI == 1) {
        int b = r0 >> 11, s = r0 & (S_-1), h = ccol >> 6, d = ccol & 63;
        ushort4 pk;
        pk.x = f2bf((acc[mi][ni][0] + bv) * oscale);
        pk.y = f2bf((acc[mi][ni][1] + bv) * oscale);
        pk.z = f2bf((acc[mi][ni][2] + bv) * oscale);
        pk.w = f2bf((acc[mi][ni][3] + bv) * oscale);
        *(ushort4*)&((ushort*)Cout)[((((size_t)b*H_ + h)*D_ + d) << 11) + s] = pk;
      } else {
        for (int j = 0; j < 4; ++j) {
          const int r = r0 + j;
          const float v = (acc[mi][ni][j] + bv) * oscale;
          if (EPI == 0) {
            int b = r >> 11, s = r & (S_-1), h = ccol >> 6, d = ccol & 63;
            ((ushort*)Cout)[((((size_t)b*H_ + h)*S_ + s) << 6) + d] = f2bf(v);
          } else {
            ((float*)Cout)[(size_t)r*E_ + ccol] = v;
          }
        }
      }
    }
}

// ---------------- causal flash attention (paired-block balanced) ----------
// Block = q-blocks {qpair, 31-qpair} (64 rows each) of one (b,h): uniform
// 33 tile-computes per block -> no causal straggler tail (r9: Occupancy 10%).
// One shared KV stream: tiles 0..31-qpair; low q-block consumes its prefix.
// Swapped QK^T (lane owns a q-row), lane-local online softmax in exp2 domain
// (scale pre-folded into Q), defer-max THR=8, cvt_pk P-pack, T14 staging.
__global__ __launch_bounds__(256)
void attn_kernel(const ushort* __restrict__ q, const ushort* __restrict__ k,
                 const ushort* __restrict__ vt, ushort* __restrict__ ao) {
  const int qpair = blockIdx.x;            // 16 pairs of 64-row q-blocks
  const int bh = blockIdx.y;
  const int b = bh >> 4, h = bh & 15;
  const int t = threadIdx.x, lane = t & 63, wave = t >> 6;
  const int g = lane >> 4, li = lane & 15;
  const int qlo0 = qpair*64      + wave*16;   // this wave's low-block rows
  const int qhi0 = (31-qpair)*64 + wave*16;   // this wave's high-block rows

  __shared__ ushort lK[64*72];             // K rows [k_local][d], pad 72
  __shared__ ushort lV[64*72];             // V^T rows [d][k_local], pad 72
  __shared__ ushort lP[4][16*72];          // per-wave P [q_local=li][k_local]

  const ushort* qp = q  + (size_t)bh * S_ * D_;
  const ushort* kp = k  + (size_t)bh * S_ * D_;
  const ushort* vp = vt + (size_t)bh * D_ * S_;

  // Q fragments (B-operand); Q already scaled by 0.125*log2(e)
  short8 qf[2][2];
  for (int ks = 0; ks < 2; ++ks) {
    qf[0][ks] = *(const short8*)&qp[(size_t)(qlo0 + li)*D_ + ks*32 + g*8];
    qf[1][ks] = *(const short8*)&qp[(size_t)(qhi0 + li)*D_ + ks*32 + g*8];
  }

  f32x4 o[2][4] = {};                      // o[mq][dt]: O[q=li-row][d=dt*16+g*4+j]
  float m_i[2] = {-3e38f, -3e38f};
  float l_i[2] = {0.f, 0.f};

  const int sr = t >> 2;                   // staging row 0..63
  const int sc = (t & 3) * 16;             // staging col 0/16/32/48

  short8 rK0, rK1, rV0, rV1;               // staging registers (T14 split)
  rK0 = *(const short8*)&kp[(size_t)sr*D_ + sc];
  rK1 = *(const short8*)&kp[(size_t)sr*D_ + sc + 8];
  rV0 = *(const short8*)&vp[(size_t)sr*S_ + sc];
  rV1 = *(const short8*)&vp[(size_t)sr*S_ + sc + 8];

  const int nkt = 32 - qpair;              // KV tiles 0..31-qpair
  for (int kt = 0; kt < nkt; ++kt) {
    const int k0 = kt * 64;
    __syncthreads();                       // consumers of previous tile done
    *(short8*)&lK[sr*72 + sc]     = rK0;
    *(short8*)&lK[sr*72 + sc + 8] = rK1;
    *(short8*)&lV[sr*72 + sc]     = rV0;
    *(short8*)&lV[sr*72 + sc + 8] = rV1;
    __syncthreads();                       // tile visible
    if (kt + 1 < nkt) {                    // prefetch next tile
      const int kn = k0 + 64;
      rK0 = *(const short8*)&kp[(size_t)(kn + sr)*D_ + sc];
      rK1 = *(const short8*)&kp[(size_t)(kn + sr)*D_ + sc + 8];
      rV0 = *(const short8*)&vp[(size_t)sr*S_ + kn + sc];
      rV1 = *(const short8*)&vp[(size_t)sr*S_ + kn + sc + 8];
    }

    const bool do_lo = (k0 <= qlo0 + 15);  // wave-uniform low-block activity
    // (high block is active for every staged tile by construction)

    // S^T: st[mq][ct] = K * Q^T ; lane holds S[k=k0+ct*16+g*4+j][q=li-row]
    f32x4 st[2][4] = {};
    for (int ks = 0; ks < 2; ++ks)
      for (int ct = 0; ct < 4; ++ct) {
        short8 kf = *(const short8*)&lK[(ct*16 + li)*72 + ks*32 + g*8];
        st[1][ct] = __builtin_amdgcn_mfma_f32_16x16x32_bf16(kf, qf[1][ks], st[1][ct], 0,0,0);
        if (do_lo)
          st[0][ct] = __builtin_amdgcn_mfma_f32_16x16x32_bf16(kf, qf[0][ks], st[0][ct], 0,0,0);
      }

    for (int mq = 0; mq < 2; ++mq) {
      if (mq == 0 && !do_lo) continue;
      const int qrow = ((mq == 0) ? qlo0 : qhi0) + li;   // this lane's q-row
      // mask + local max (values already in exp2 domain)
      float mx = -3e38f;
      for (int ct = 0; ct < 4; ++ct)
        for (int j = 0; j < 4; ++j) {
          const int kk = k0 + ct*16 + g*4 + j;
          float x = st[mq][ct][j];
          x = (kk <= qrow) ? x : -3e38f;
          st[mq][ct][j] = x;
          mx = fmaxf(mx, x);
        }
      mx = fmaxf(mx, __shfl_xor(mx, 16, 64));
      mx = fmaxf(mx, __shfl_xor(mx, 32, 64));
      // defer-max: rescale only when max grows past THR=8 (P bounded by 2^8)
      if (__any(mx > m_i[mq] + 8.0f)) {
        const float mn = fmaxf(m_i[mq], mx);
        const float alpha = exp2f(m_i[mq] - mn);
        m_i[mq] = mn;
        l_i[mq] *= alpha;
        for (int dt = 0; dt < 4; ++dt)
          for (int j = 0; j < 4; ++j) o[mq][dt][j] *= alpha;
      }
      const float mcur = m_i[mq];
      // P = 2^(S - m), row-sum, pack pairs via v_cvt_pk_bf16_f32
      float rs = 0.f;
      for (int ct = 0; ct < 4; ++ct) {
        float p0 = exp2f(st[mq][ct][0] - mcur);
        float p1 = exp2f(st[mq][ct][1] - mcur);
        float p2 = exp2f(st[mq][ct][2] - mcur);
        float p3 = exp2f(st[mq][ct][3] - mcur);
        rs += (p0 + p1) + (p2 + p3);
        uint32_t w0, w1;
        asm("v_cvt_pk_bf16_f32 %0, %1, %2" : "=v"(w0) : "v"(p0), "v"(p1));
        asm("v_cvt_pk_bf16_f32 %0, %1, %2" : "=v"(w1) : "v"(p2), "v"(p3));
        *(uint32_t*)&lP[wave][li*72 + ct*16 + g*4]     = w0;
        *(uint32_t*)&lP[wave][li*72 + ct*16 + g*4 + 2] = w1;
      }
      rs += __shfl_xor(rs, 16, 64);
      rs += __shfl_xor(rs, 32, 64);
      l_i[mq] += rs;
      // O^T += V^T * P^T (same-wave lP write->read ordered by lgkmcnt)
      for (int ks2 = 0; ks2 < 2; ++ks2) {
        short8 pf = *(const short8*)&lP[wave][li*72 + ks2*32 + g*8];
        for (int dt = 0; dt < 4; ++dt) {
          short8 vf = *(const short8*)&lV[(dt*16 + li)*72 + ks2*32 + g*8];
          o[mq][dt] = __builtin_amdgcn_mfma_f32_16x16x32_bf16(vf, pf, o[mq][dt], 0,0,0);
        }
      }
    }
  }

  // finalize: O /= l (lane-local), write bf16 [B,S,E]; 4 consecutive d
  for (int mq = 0; mq < 2; ++mq) {
    const float inv_l = 1.0f / l_i[mq];
    const int row = ((mq == 0) ? qlo0 : qhi0) + li;
    for (int dt = 0; dt < 4; ++dt) {
      ushort4 pk;
      pk.x = f2bf(o[mq][dt][0] * inv_l);
      pk.y = f2bf(o[mq][dt][1] * inv_l);
      pk.z = f2bf(o[mq][dt][2] * inv_l);
      pk.w = f2bf(o[mq][dt][3] * inv_l);
      *(ushort4*)&ao[((size_t)b*S_ + row)*E_ + h*D_ + dt*16 + g*4] = pk;
    }
  }
}

// ---------------- launch ----------------
extern "C" void kernel_launch(void* const* d_in, const int* in_sizes, int n_in,
                              void* d_out, int out_size, void* d_ws, size_t ws_size,
                              hipStream_t stream) {
  (void)in_sizes; (void)n_in; (void)out_size; (void)ws_size;
  const float* x  = (const float*)d_in[0];
  const float* Wq = (const float*)d_in[1];
  const float* bq = (const float*)d_in[2];
  const float* Wk = (const float*)d_in[3];
  const float* bk = (const float*)d_in[4];
  const float* Wv = (const float*)d_in[5];
  const float* bv = (const float*)d_in[6];
  const float* Wo = (const float*)d_in[7];
  const float* bo = (const float*)d_in[8];
  float* out = (float*)d_out;

  char* ws = (char*)d_ws;
  ushort* xb  = (ushort*)(ws);                    // x bf16          16 MB
  ushort* wqb = (ushort*)(ws + 16777216);         // Wq bf16          2 MB
  ushort* wkb = (ushort*)(ws + 18874368);
  ushort* wvb = (ushort*)(ws + 20971520);
  ushort* wob = (ushort*)(ws + 23068672);
  ushort* qb_ = (ushort*)(ws + 25165824);         // Q [B,H,S,D]     16 MB
  ushort* kb_ = (ushort*)(ws + 41943040);         // K [B,H,S,D]     16 MB
  ushort* vtb = (ushort*)(ws + 58720256);         // V [B,H,D,S]     16 MB
  ushort* aob = xb;                               // attn out aliases xb (x dead)

  cast_bf16_kernel<<<8192, 256, 0, stream>>>(x,  xb,  N_*E_/4);
  cast_bf16_kernel<<<1024, 256, 0, stream>>>(Wq, wqb, E_*E_/4);
  cast_bf16_kernel<<<1024, 256, 0, stream>>>(Wk, wkb, E_*E_/4);
  cast_bf16_kernel<<<1024, 256, 0, stream>>>(Wv, wvb, E_*E_/4);
  cast_bf16_kernel<<<1024, 256, 0, stream>>>(Wo, wob, E_*E_/4);

  const float QSCALE = 0.125f * 1.44269504f;   // softmax scale * log2(e)
  dim3 gg(N_/128, E_/128);   // 64 x 8
  gemm_bt<0><<<gg, 256, 0, stream>>>(xb, wqb, bq, qb_, QSCALE);
  gemm_bt<0><<<gg, 256, 0, stream>>>(xb, wkb, bk, kb_, 1.0f);
  gemm_bt<1><<<gg, 256, 0, stream>>>(xb, wvb, bv, vtb, 1.0f);

  attn_kernel<<<dim3(16, B_*H_), 256, 0, stream>>>(qb_, kb_, vtb, aob);

  gemm_bt<2><<<gg, 256, 0, stream>>>(aob, wob, bo, out, 1.0f);
}